// Round 8
// baseline (435.385 us; speedup 1.0000x reference)
//
#include <hip/hip_runtime.h>
#include <math.h>

#define HD 128

union F4 { float4 v; float f[4]; };

typedef __attribute__((ext_vector_type(8))) short bf8_t;   // 8 bf16 (4 VGPRs)
typedef __attribute__((ext_vector_type(4))) float f4_t;    // MFMA C/D

__device__ __forceinline__ unsigned short f2bf(float f){   // RNE fp32->bf16
  unsigned int u = __float_as_uint(f);
  return (unsigned short)((u + 0x7fffu + ((u>>16)&1u)) >> 16);
}

// dot of fp32 h[0..3] with 4 bf16 weights packed in two u32s (i-major pairs)
__device__ __forceinline__ float dotbf(const F4& h, unsigned int ua, unsigned int ub){
  float w0 = __uint_as_float(ua << 16);
  float w1 = __uint_as_float(ua & 0xffff0000u);
  float w2 = __uint_as_float(ub << 16);
  float w3 = __uint_as_float(ub & 0xffff0000u);
  return fmaf(h.f[0], w0, fmaf(h.f[1], w1, fmaf(h.f[2], w2, h.f[3]*w3)));
}

// ---------------- fused prep: gather + count + W transposes(bf16) + loop-W pack ----------------
__device__ __forceinline__ void wpack_one(const float* __restrict__ W,
                                          unsigned short* __restrict__ Wp, int t, int NO){
  int lane = t & 63, ks = (t>>6) & 3, ct = t >> 8;
  int k0 = ks*32 + (lane>>4)*8, col = ct*16 + (lane&15);
  unsigned short v[8];
  #pragma unroll
  for (int j=0;j<8;++j) v[j] = f2bf(W[(k0+j)*NO + col]);
  ushort4* dst = (ushort4*)&Wp[(size_t)t*8];
  dst[0] = make_ushort4(v[0],v[1],v[2],v[3]);
  dst[1] = make_ushort4(v[4],v[5],v[6],v[7]);
}

__global__ void k_prep(const int* __restrict__ ids, const float4* __restrict__ emb4,
                       float4* __restrict__ h0, unsigned short* __restrict__ h0b,
                       const int* __restrict__ dst, int* __restrict__ counts,
                       const float* __restrict__ W1, unsigned short* __restrict__ W1Tb,
                       const float* __restrict__ W2, unsigned short* __restrict__ W2Tb,
                       const float* __restrict__ lw1, unsigned short* __restrict__ W1p,
                       const float* __restrict__ lw2, unsigned short* __restrict__ W2p,
                       int NG, int E, int n1, int n2){
  int i = blockIdx.x*256 + threadIdx.x;
  if (i < NG){                                   // gather h0 (f32 + bf16)
    int row = i>>5, c = i&31;
    float4 v = emb4[ids[row]*32 + c];
    h0[i] = v;
    *(ushort4*)&h0b[(size_t)i*4] = make_ushort4(f2bf(v.x),f2bf(v.y),f2bf(v.z),f2bf(v.w));
    return;
  }
  i -= NG;
  if (i < E){ atomicAdd(&counts[dst[i]], 1); return; }
  i -= E;
  if (i < n1){                                   // W1 (rb,i,o)->(rb,o,i) bf16
    int ii = i & 3, o = (i>>2) & 3, rb = i>>4;
    W1Tb[i] = f2bf(W1[rb*16 + ii*4 + o]);
    return;
  }
  i -= n1;
  if (i < n2){                                   // W2 (rb,i,o)->(rb,o,i) bf16
    int ii = i & 3, o = (i>>2) & 7, rb = i>>5;
    W2Tb[i] = f2bf(W2[rb*32 + ii*8 + o]);
    return;
  }
  i -= n2;
  if (i < 2048){ wpack_one(lw1, W1p, i, 128); return; }
  i -= 2048;
  if (i < 4096){ wpack_one(lw2, W2p, i, 256); }
}

// ---------------- CSR scan chain ----------------
__global__ void k_scan_block(const int* __restrict__ counts, int* __restrict__ scanTmp,
                             int* __restrict__ blockSums, int n){
  __shared__ int sm[256];
  int i = blockIdx.x*256 + threadIdx.x;
  int v = (i<n)?counts[i]:0;
  sm[threadIdx.x]=v; __syncthreads();
  for (int ofs=1; ofs<256; ofs<<=1){
    int t = (threadIdx.x>=ofs)?sm[threadIdx.x-ofs]:0;
    __syncthreads();
    sm[threadIdx.x]+=t;
    __syncthreads();
  }
  if (i<n) scanTmp[i]=sm[threadIdx.x];
  if (threadIdx.x==255) blockSums[blockIdx.x]=sm[255];
}

__global__ void k_scan_top(int* __restrict__ blockSums, int nb){
  __shared__ int sm[1024];
  int v = ((int)threadIdx.x<nb)?blockSums[threadIdx.x]:0;
  sm[threadIdx.x]=v; __syncthreads();
  for (int ofs=1; ofs<1024; ofs<<=1){
    int t = ((int)threadIdx.x>=ofs)?sm[threadIdx.x-ofs]:0;
    __syncthreads();
    sm[threadIdx.x]+=t;
    __syncthreads();
  }
  if ((int)threadIdx.x<nb) blockSums[threadIdx.x] = sm[threadIdx.x]-v; // exclusive
}

__global__ void k_scan_fin(const int* __restrict__ scanTmp, const int* __restrict__ blockSums,
                           const int* __restrict__ counts,
                           int* __restrict__ row_ptr, int* __restrict__ cursors, int n){
  int i = blockIdx.x*256 + threadIdx.x;
  if (i<n){
    int incl = scanTmp[i] + blockSums[blockIdx.x];
    row_ptr[i+1] = incl;
    cursors[i] = incl - counts[i];
  }
  if (i==0) row_ptr[0]=0;
}

__global__ void k_scatter(const int* __restrict__ dst, const int* __restrict__ src,
                          const int* __restrict__ et, const float* __restrict__ norm,
                          int* __restrict__ cursors, int4* __restrict__ pay, int E){
  int e = blockIdx.x*256 + threadIdx.x;
  if (e<E){
    int p = atomicAdd(&cursors[dst[e]],1);
    pay[p] = make_int4(src[e], et[e], __float_as_int(norm[e]), 0);
  }
}

// ---------------- edge aggregation: one wave per dst row, 2 edges in parallel ----------------
// Half h (32 lanes) owns edge e0+2i+h; lane b = bdd block; lane computes all of
// its block's outputs. Weights bf16 (halved L2 bytes), h fp32. Cross-half sum
// via shfl_xor(32) at the end; half 0 stores.
__global__ __launch_bounds__(256)
void k_edge1(const int* __restrict__ row_ptr, const int4* __restrict__ pay,
             const float* __restrict__ h, const unsigned short* __restrict__ WTb,
             float* __restrict__ agg, int Nn){
  int wid = __builtin_amdgcn_readfirstlane((blockIdx.x*256 + threadIdx.x)>>6);
  if (wid >= Nn) return;
  const int lane = threadIdx.x & 63;
  const int half = lane >> 5, b = lane & 31;
  const int e0 = row_ptr[wid], e1 = row_ptr[wid+1];
  float a0=0.f, a1=0.f, a2=0.f, a3=0.f;
  int e = e0 + half;
  int4 p;
  if (e < e1) p = pay[e];
  for (; e < e1; e += 2){
    int4 pn = (e+2 < e1) ? pay[e+2] : p;
    float nm = __int_as_float(p.z);
    F4 hv; hv.v = *(const float4*)&h[(size_t)p.x*HD + b*4];
    const uint4* wq = (const uint4*)&WTb[(size_t)p.y*512 + b*16];
    uint4 q0 = wq[0], q1 = wq[1];
    a0 = fmaf(nm, dotbf(hv, q0.x, q0.y), a0);
    a1 = fmaf(nm, dotbf(hv, q0.z, q0.w), a1);
    a2 = fmaf(nm, dotbf(hv, q1.x, q1.y), a2);
    a3 = fmaf(nm, dotbf(hv, q1.z, q1.w), a3);
    p = pn;
  }
  a0 += __shfl_xor(a0, 32); a1 += __shfl_xor(a1, 32);
  a2 += __shfl_xor(a2, 32); a3 += __shfl_xor(a3, 32);
  if (half == 0){
    F4 o; o.f[0]=a0; o.f[1]=a1; o.f[2]=a2; o.f[3]=a3;
    *(float4*)&agg[(size_t)wid*128 + b*4] = o.v;   // col = b*4+o
  }
}

__global__ __launch_bounds__(256)
void k_edge2(const int* __restrict__ row_ptr, const int4* __restrict__ pay,
             const float* __restrict__ h, const unsigned short* __restrict__ WTb,
             float* __restrict__ agg, int Nn){
  int wid = __builtin_amdgcn_readfirstlane((blockIdx.x*256 + threadIdx.x)>>6);
  if (wid >= Nn) return;
  const int lane = threadIdx.x & 63;
  const int half = lane >> 5, b = lane & 31;
  const int e0 = row_ptr[wid], e1 = row_ptr[wid+1];
  float acc[8];
  #pragma unroll
  for (int o=0;o<8;++o) acc[o]=0.f;
  int e = e0 + half;
  int4 p;
  if (e < e1) p = pay[e];
  for (; e < e1; e += 2){
    int4 pn = (e+2 < e1) ? pay[e+2] : p;
    float nm = __int_as_float(p.z);
    F4 hv; hv.v = *(const float4*)&h[(size_t)p.x*HD + b*4];
    const uint4* wq = (const uint4*)&WTb[(size_t)p.y*1024 + b*32];
    uint4 q0 = wq[0], q1 = wq[1], q2 = wq[2], q3 = wq[3];
    acc[0] = fmaf(nm, dotbf(hv, q0.x, q0.y), acc[0]);
    acc[1] = fmaf(nm, dotbf(hv, q0.z, q0.w), acc[1]);
    acc[2] = fmaf(nm, dotbf(hv, q1.x, q1.y), acc[2]);
    acc[3] = fmaf(nm, dotbf(hv, q1.z, q1.w), acc[3]);
    acc[4] = fmaf(nm, dotbf(hv, q2.x, q2.y), acc[4]);
    acc[5] = fmaf(nm, dotbf(hv, q2.z, q2.w), acc[5]);
    acc[6] = fmaf(nm, dotbf(hv, q3.x, q3.y), acc[6]);
    acc[7] = fmaf(nm, dotbf(hv, q3.z, q3.w), acc[7]);
    p = pn;
  }
  #pragma unroll
  for (int o=0;o<8;++o) acc[o] += __shfl_xor(acc[o], 32);
  if (half == 0){
    F4 o0, o1;
    #pragma unroll
    for (int j=0;j<4;++j){ o0.f[j]=acc[j]; o1.f[j]=acc[4+j]; }
    *(float4*)&agg[(size_t)wid*256 + b*8]     = o0.v;   // col = b*8+o
    *(float4*)&agg[(size_t)wid*256 + b*8 + 4] = o1.v;
  }
}

// ---------------- MFMA self-loop GEMMs (bf16 in, fp32 accum) ----------------
// A-frag (16x16x32): lane holds A[row=lane&15][k=(lane>>4)*8+j] -> 16B load from
// row-major bf16 A. B-frag pre-packed (Wp). C: col=lane&15, row=(lane>>4)*4+r.
__global__ __launch_bounds__(256)
void k_mfma_relu(const unsigned short* __restrict__ Ab, const unsigned short* __restrict__ Wp,
                 const float* __restrict__ agg, const float* __restrict__ bias,
                 float* __restrict__ out, unsigned short* __restrict__ outb, int M){
  const int lane = threadIdx.x & 63;
  const int rowBase = blockIdx.x*64 + (threadIdx.x>>6)*16;
  const int ar = lane & 15, kg = lane >> 4;
  const int aclamp = min(rowBase + ar, M-1);
  f4_t acc[8];
  #pragma unroll
  for (int ct=0; ct<8; ++ct) acc[ct] = (f4_t)0.f;
  #pragma unroll
  for (int ks=0; ks<4; ++ks){
    bf8_t a = *(const bf8_t*)&Ab[(size_t)aclamp*HD + ks*32 + kg*8];
    #pragma unroll
    for (int ct=0; ct<8; ++ct){
      bf8_t b = *(const bf8_t*)&Wp[(size_t)((ct*4 + ks)*64 + lane)*8];
      acc[ct] = __builtin_amdgcn_mfma_f32_16x16x32_bf16(a, b, acc[ct], 0,0,0);
    }
  }
  const int crow = rowBase + kg*4;
  #pragma unroll
  for (int r=0; r<4; ++r){
    int gr = crow + r;
    if (gr >= M) continue;
    #pragma unroll
    for (int ct=0; ct<8; ++ct){
      int col = ct*16 + ar;
      float v = fmaxf(acc[ct][r] + agg[(size_t)gr*128 + col] + bias[col], 0.f);
      out[(size_t)gr*128 + col] = v;
      outb[(size_t)gr*128 + col] = f2bf(v);
    }
  }
}

__global__ __launch_bounds__(256)
void k_mfma_gauss(const unsigned short* __restrict__ Ab, const unsigned short* __restrict__ Wp,
                  const float* __restrict__ agg, const float* __restrict__ bias,
                  const float* __restrict__ eps, float* __restrict__ out, int M){
  const int lane = threadIdx.x & 63;
  const int bx = blockIdx.x & 1;
  const int rowBase = (blockIdx.x>>1)*64 + (threadIdx.x>>6)*16;
  const int ar = lane & 15, kg = lane >> 4;
  const int aclamp = min(rowBase + ar, M-1);
  f4_t accm[4], acch[4];
  #pragma unroll
  for (int ct=0; ct<4; ++ct){ accm[ct] = (f4_t)0.f; acch[ct] = (f4_t)0.f; }
  #pragma unroll
  for (int ks=0; ks<4; ++ks){
    bf8_t a = *(const bf8_t*)&Ab[(size_t)aclamp*HD + ks*32 + kg*8];
    #pragma unroll
    for (int ct=0; ct<4; ++ct){
      int ctm = bx*4 + ct, cth = 8 + bx*4 + ct;
      bf8_t bm = *(const bf8_t*)&Wp[(size_t)((ctm*4 + ks)*64 + lane)*8];
      bf8_t bh = *(const bf8_t*)&Wp[(size_t)((cth*4 + ks)*64 + lane)*8];
      accm[ct] = __builtin_amdgcn_mfma_f32_16x16x32_bf16(a, bm, accm[ct], 0,0,0);
      acch[ct] = __builtin_amdgcn_mfma_f32_16x16x32_bf16(a, bh, acch[ct], 0,0,0);
    }
  }
  const int crow = rowBase + kg*4;
  #pragma unroll
  for (int r=0; r<4; ++r){
    int gr = crow + r;
    if (gr >= M) continue;
    #pragma unroll
    for (int ct=0; ct<4; ++ct){
      int colm = bx*64 + ct*16 + ar;
      float m  = accm[ct][r] + agg[(size_t)gr*256 + colm]       + bias[colm];
      float hp = acch[ct][r] + agg[(size_t)gr*256 + colm + 128] + bias[colm+128];
      float sp = fmaxf(hp, 0.f) + log1pf(expf(-fabsf(hp)));  // stable softplus
      out[(size_t)gr*128 + colm] = fmaf(sqrtf(sp + 1e-8f), eps[(size_t)gr*128 + colm], m);
    }
  }
}

extern "C" void kernel_launch(void* const* d_in, const int* in_sizes, int n_in,
                              void* d_out, int out_size, void* d_ws, size_t ws_size,
                              hipStream_t stream){
  (void)n_in; (void)out_size; (void)ws_size;
  const int*   node_ids = (const int*)d_in[0];
  const int*   src  = (const int*)d_in[1];
  const int*   dst  = (const int*)d_in[2];
  const int*   et   = (const int*)d_in[3];
  const float* norm = (const float*)d_in[4];
  const float* emb  = (const float*)d_in[5];
  const float* W1   = (const float*)d_in[6];
  const float* lw1  = (const float*)d_in[7];
  const float* b1   = (const float*)d_in[8];
  const float* W2   = (const float*)d_in[9];
  const float* lw2  = (const float*)d_in[10];
  const float* b2   = (const float*)d_in[11];
  const float* eps  = (const float*)d_in[12];
  float* out = (float*)d_out;

  const int N  = in_sizes[0];
  const int E  = in_sizes[1];
  const int n1 = in_sizes[6];    // R*B*4*4
  const int n2 = in_sizes[9];    // R*B*4*8

  // workspace layout (bytes):
  // [0, 2*szNH)        : h0 (first szNH; dead after mfma_relu) / agg2 (full 2*szNH)
  // [2*szNH, 3*szNH)   : h1 (f32)
  // [3*szNH, 4*szNH)   : agg1
  // then: pay | CSR ints | W1Tb | W2Tb (bf16) | W1p | W2p | h0b | h1b
  char* w = (char*)d_ws;
  size_t szNH = (size_t)N*HD*sizeof(float);
  float* h0   = (float*)(w);
  float* agg2 = (float*)(w);
  float* h1   = (float*)(w + 2*szNH);
  float* agg1 = (float*)(w + 3*szNH);
  char*  ip   = w + 4*szNH;
  int4*  pay       = (int4*)ip;
  int*   counts    = (int*)(pay + E);
  int*   scanTmp   = counts + N;
  int*   row_ptr   = scanTmp + N;
  int*   cursors   = row_ptr + (N+1);
  int*   blockSums = cursors + N;
  size_t tail      = ((size_t)((char*)(blockSums + 1024) - w) + 63) & ~(size_t)63;
  unsigned short* W1Tb = (unsigned short*)(w + tail);
  unsigned short* W2Tb = W1Tb + n1;
  unsigned short* W1p  = W2Tb + n2;            //  8*256*8 ushorts
  unsigned short* W2p  = W1p + 8*256*8;        // 16*256*8 ushorts
  unsigned short* h0b  = W2p + 16*256*8;
  unsigned short* h1b  = h0b + (size_t)N*HD;

  hipMemsetAsync(counts, 0, (size_t)N*sizeof(int), stream);

  const int NG = N*32;
  const int Tprep = NG + E + n1 + n2 + 2048 + 4096;
  int nb_e    = (E+255)/256;
  int nb_scan = (N+255)/256;   // 391 (<1024, single-level top scan ok)

  k_prep<<<(Tprep+255)/256, 256, 0, stream>>>(node_ids, (const float4*)emb, (float4*)h0, h0b,
                                              dst, counts, W1, W1Tb, W2, W2Tb,
                                              lw1, W1p, lw2, W2p, NG, E, n1, n2);
  k_scan_block<<<nb_scan, 256, 0, stream>>>(counts, scanTmp, blockSums, N);
  k_scan_top<<<1, 1024, 0, stream>>>(blockSums, nb_scan);
  k_scan_fin<<<nb_scan, 256, 0, stream>>>(scanTmp, blockSums, counts, row_ptr, cursors, N);
  k_scatter<<<nb_e, 256, 0, stream>>>(dst, src, et, norm, cursors, pay, E);

  int nb_rows = (N+3)/4;        // one 64-lane wave per dst row, 4 waves/block
  int nb_m    = (N+63)/64;      // 64 rows per MFMA block

  k_edge1<<<nb_rows, 256, 0, stream>>>(row_ptr, pay, h0, W1Tb, agg1, N);
  k_mfma_relu<<<nb_m, 256, 0, stream>>>(h0b, W1p, agg1, b1, h1, h1b, N);
  k_edge2<<<nb_rows, 256, 0, stream>>>(row_ptr, pay, h1, W2Tb, agg2, N);
  k_mfma_gauss<<<nb_m*2, 256, 0, stream>>>(h1b, W2p, agg2, b2, eps, out, N);
}

// Round 9
// 434.429 us; speedup vs baseline: 1.0022x; 1.0022x over previous
//
#include <hip/hip_runtime.h>
#include <math.h>

#define HD 128

union F4 { float4 v; float f[4]; };

typedef __attribute__((ext_vector_type(8))) short bf8_t;   // 8 bf16 (4 VGPRs)
typedef __attribute__((ext_vector_type(4))) float f4_t;    // MFMA C/D

__device__ __forceinline__ unsigned short f2bf(float f){   // RNE fp32->bf16
  unsigned int u = __float_as_uint(f);
  return (unsigned short)((u + 0x7fffu + ((u>>16)&1u)) >> 16);
}
__device__ __forceinline__ float bflo(unsigned int u){ return __uint_as_float(u << 16); }
__device__ __forceinline__ float bfhi(unsigned int u){ return __uint_as_float(u & 0xffff0000u); }

// dot of fp32 h[0..3] with 4 bf16 weights packed in two u32s
__device__ __forceinline__ float dotbf(const F4& h, unsigned int ua, unsigned int ub){
  return fmaf(h.f[0], bflo(ua), fmaf(h.f[1], bfhi(ua), fmaf(h.f[2], bflo(ub), h.f[3]*bfhi(ub))));
}

// ---------------- fused prep: gather(bf16) + count + W transposes(bf16) + loop-W pack ----------------
__device__ __forceinline__ void wpack_one(const float* __restrict__ W,
                                          unsigned short* __restrict__ Wp, int t, int NO){
  int lane = t & 63, ks = (t>>6) & 3, ct = t >> 8;
  int k0 = ks*32 + (lane>>4)*8, col = ct*16 + (lane&15);
  unsigned short v[8];
  #pragma unroll
  for (int j=0;j<8;++j) v[j] = f2bf(W[(k0+j)*NO + col]);
  ushort4* dst = (ushort4*)&Wp[(size_t)t*8];
  dst[0] = make_ushort4(v[0],v[1],v[2],v[3]);
  dst[1] = make_ushort4(v[4],v[5],v[6],v[7]);
}

__global__ void k_prep(const int* __restrict__ ids, const float4* __restrict__ emb4,
                       unsigned short* __restrict__ h0b,
                       const int* __restrict__ dst, int* __restrict__ counts,
                       const float* __restrict__ W1, unsigned short* __restrict__ W1Tb,
                       const float* __restrict__ W2, unsigned short* __restrict__ W2Tb,
                       const float* __restrict__ lw1, unsigned short* __restrict__ W1p,
                       const float* __restrict__ lw2, unsigned short* __restrict__ W2p,
                       int NG, int E, int n1, int n2){
  int i = blockIdx.x*256 + threadIdx.x;
  if (i < NG){                                   // gather h0 (bf16 only)
    int row = i>>5, c = i&31;
    float4 v = emb4[ids[row]*32 + c];
    *(ushort4*)&h0b[(size_t)i*4] = make_ushort4(f2bf(v.x),f2bf(v.y),f2bf(v.z),f2bf(v.w));
    return;
  }
  i -= NG;
  if (i < E){ atomicAdd(&counts[dst[i]], 1); return; }
  i -= E;
  if (i < n1){                                   // W1 (rb,i,o)->(rb,o,i) bf16
    int ii = i & 3, o = (i>>2) & 3, rb = i>>4;
    W1Tb[i] = f2bf(W1[rb*16 + ii*4 + o]);
    return;
  }
  i -= n1;
  if (i < n2){                                   // W2 (rb,i,o)->(rb,o,i) bf16
    int ii = i & 3, o = (i>>2) & 7, rb = i>>5;
    W2Tb[i] = f2bf(W2[rb*32 + ii*8 + o]);
    return;
  }
  i -= n2;
  if (i < 2048){ wpack_one(lw1, W1p, i, 128); return; }
  i -= 2048;
  if (i < 4096){ wpack_one(lw2, W2p, i, 256); }
}

// ---------------- CSR scan chain ----------------
__global__ void k_scan_block(const int* __restrict__ counts, int* __restrict__ scanTmp,
                             int* __restrict__ blockSums, int n){
  __shared__ int sm[256];
  int i = blockIdx.x*256 + threadIdx.x;
  int v = (i<n)?counts[i]:0;
  sm[threadIdx.x]=v; __syncthreads();
  for (int ofs=1; ofs<256; ofs<<=1){
    int t = (threadIdx.x>=ofs)?sm[threadIdx.x-ofs]:0;
    __syncthreads();
    sm[threadIdx.x]+=t;
    __syncthreads();
  }
  if (i<n) scanTmp[i]=sm[threadIdx.x];
  if (threadIdx.x==255) blockSums[blockIdx.x]=sm[255];
}

__global__ void k_scan_top(int* __restrict__ blockSums, int nb){
  __shared__ int sm[1024];
  int v = ((int)threadIdx.x<nb)?blockSums[threadIdx.x]:0;
  sm[threadIdx.x]=v; __syncthreads();
  for (int ofs=1; ofs<1024; ofs<<=1){
    int t = ((int)threadIdx.x>=ofs)?sm[threadIdx.x-ofs]:0;
    __syncthreads();
    sm[threadIdx.x]+=t;
    __syncthreads();
  }
  if ((int)threadIdx.x<nb) blockSums[threadIdx.x] = sm[threadIdx.x]-v; // exclusive
}

__global__ void k_scan_fin(const int* __restrict__ scanTmp, const int* __restrict__ blockSums,
                           const int* __restrict__ counts,
                           int* __restrict__ row_ptr, int* __restrict__ cursors, int n){
  int i = blockIdx.x*256 + threadIdx.x;
  if (i<n){
    int incl = scanTmp[i] + blockSums[blockIdx.x];
    row_ptr[i+1] = incl;
    cursors[i] = incl - counts[i];
  }
  if (i==0) row_ptr[0]=0;
}

__global__ void k_scatter(const int* __restrict__ dst, const int* __restrict__ src,
                          const int* __restrict__ et, const float* __restrict__ norm,
                          int* __restrict__ cursors, int4* __restrict__ pay, int E){
  int e = blockIdx.x*256 + threadIdx.x;
  if (e<E){
    int p = atomicAdd(&cursors[dst[e]],1);
    pay[p] = make_int4(src[e], et[e], __float_as_int(norm[e]), 0);
  }
}

// ---------------- edge aggregation: one wave per dst row, 4 edges in parallel ----------------
// 16-lane group g owns edge e0+4*it+g; lane-in-group l owns bdd blocks 2l,2l+1.
// h bf16: one 16B load covers both blocks. W bf16 contiguous. Cross-group sum
// via shfl_xor(16)+shfl_xor(32); group 0 stores.
__global__ __launch_bounds__(256)
void k_edge1(const int* __restrict__ row_ptr, const int4* __restrict__ pay,
             const unsigned short* __restrict__ h, const unsigned short* __restrict__ WTb,
             float* __restrict__ agg, int Nn){
  int wid = __builtin_amdgcn_readfirstlane((blockIdx.x*256 + threadIdx.x)>>6);
  if (wid >= Nn) return;
  const int lane = threadIdx.x & 63;
  const int g = lane >> 4, l = lane & 15;
  const int e0 = row_ptr[wid], e1 = row_ptr[wid+1];
  const int cnt = e1 - e0;
  float acc[8];
  #pragma unroll
  for (int o=0;o<8;++o) acc[o]=0.f;
  const int T = (cnt + 3) >> 2;
  int4 p;
  if (cnt > 0) p = pay[min(e0 + g, e1-1)];
  for (int it=0; it<T; ++it){
    int base = e0 + it*4 + g;
    float nm = (base < e1) ? __int_as_float(p.z) : 0.f;
    int4 pn = p;
    if (it+1 < T) pn = pay[min(base + 4, e1-1)];
    uint4 hq = *(const uint4*)&h[(size_t)p.x*HD + l*8];
    const uint4* wq = (const uint4*)&WTb[(size_t)p.y*512 + l*32];
    uint4 w0 = wq[0], w1 = wq[1], w2 = wq[2], w3 = wq[3];
    F4 hlo, hhi;
    hlo.f[0]=bflo(hq.x); hlo.f[1]=bfhi(hq.x); hlo.f[2]=bflo(hq.y); hlo.f[3]=bfhi(hq.y);
    hhi.f[0]=bflo(hq.z); hhi.f[1]=bfhi(hq.z); hhi.f[2]=bflo(hq.w); hhi.f[3]=bfhi(hq.w);
    acc[0]=fmaf(nm, dotbf(hlo,w0.x,w0.y), acc[0]);
    acc[1]=fmaf(nm, dotbf(hlo,w0.z,w0.w), acc[1]);
    acc[2]=fmaf(nm, dotbf(hlo,w1.x,w1.y), acc[2]);
    acc[3]=fmaf(nm, dotbf(hlo,w1.z,w1.w), acc[3]);
    acc[4]=fmaf(nm, dotbf(hhi,w2.x,w2.y), acc[4]);
    acc[5]=fmaf(nm, dotbf(hhi,w2.z,w2.w), acc[5]);
    acc[6]=fmaf(nm, dotbf(hhi,w3.x,w3.y), acc[6]);
    acc[7]=fmaf(nm, dotbf(hhi,w3.z,w3.w), acc[7]);
    p = pn;
  }
  #pragma unroll
  for (int o=0;o<8;++o){ acc[o] += __shfl_xor(acc[o],16); acc[o] += __shfl_xor(acc[o],32); }
  if (g == 0){
    F4 o0, o1;
    #pragma unroll
    for (int j=0;j<4;++j){ o0.f[j]=acc[j]; o1.f[j]=acc[4+j]; }
    *(float4*)&agg[(size_t)wid*128 + l*8]     = o0.v;  // block 2l -> cols 8l..8l+3
    *(float4*)&agg[(size_t)wid*128 + l*8 + 4] = o1.v;  // block 2l+1
  }
}

__global__ __launch_bounds__(256)
void k_edge2(const int* __restrict__ row_ptr, const int4* __restrict__ pay,
             const unsigned short* __restrict__ h, const unsigned short* __restrict__ WTb,
             float* __restrict__ agg, int Nn){
  int wid = __builtin_amdgcn_readfirstlane((blockIdx.x*256 + threadIdx.x)>>6);
  if (wid >= Nn) return;
  const int lane = threadIdx.x & 63;
  const int g = lane >> 4, l = lane & 15;
  const int e0 = row_ptr[wid], e1 = row_ptr[wid+1];
  const int cnt = e1 - e0;
  float acc[16];
  #pragma unroll
  for (int o=0;o<16;++o) acc[o]=0.f;
  const int T = (cnt + 3) >> 2;
  int4 p;
  if (cnt > 0) p = pay[min(e0 + g, e1-1)];
  for (int it=0; it<T; ++it){
    int base = e0 + it*4 + g;
    float nm = (base < e1) ? __int_as_float(p.z) : 0.f;
    int4 pn = p;
    if (it+1 < T) pn = pay[min(base + 4, e1-1)];
    uint4 hq = *(const uint4*)&h[(size_t)p.x*HD + l*8];
    const uint4* wq = (const uint4*)&WTb[(size_t)p.y*1024 + l*64];
    uint4 wa0 = wq[0], wa1 = wq[1], wa2 = wq[2], wa3 = wq[3];   // block 2l, o=0..7
    uint4 wb0 = wq[4], wb1 = wq[5], wb2 = wq[6], wb3 = wq[7];   // block 2l+1
    F4 hlo, hhi;
    hlo.f[0]=bflo(hq.x); hlo.f[1]=bfhi(hq.x); hlo.f[2]=bflo(hq.y); hlo.f[3]=bfhi(hq.y);
    hhi.f[0]=bflo(hq.z); hhi.f[1]=bfhi(hq.z); hhi.f[2]=bflo(hq.w); hhi.f[3]=bfhi(hq.w);
    acc[0] =fmaf(nm, dotbf(hlo,wa0.x,wa0.y), acc[0]);
    acc[1] =fmaf(nm, dotbf(hlo,wa0.z,wa0.w), acc[1]);
    acc[2] =fmaf(nm, dotbf(hlo,wa1.x,wa1.y), acc[2]);
    acc[3] =fmaf(nm, dotbf(hlo,wa1.z,wa1.w), acc[3]);
    acc[4] =fmaf(nm, dotbf(hlo,wa2.x,wa2.y), acc[4]);
    acc[5] =fmaf(nm, dotbf(hlo,wa2.z,wa2.w), acc[5]);
    acc[6] =fmaf(nm, dotbf(hlo,wa3.x,wa3.y), acc[6]);
    acc[7] =fmaf(nm, dotbf(hlo,wa3.z,wa3.w), acc[7]);
    acc[8] =fmaf(nm, dotbf(hhi,wb0.x,wb0.y), acc[8]);
    acc[9] =fmaf(nm, dotbf(hhi,wb0.z,wb0.w), acc[9]);
    acc[10]=fmaf(nm, dotbf(hhi,wb1.x,wb1.y), acc[10]);
    acc[11]=fmaf(nm, dotbf(hhi,wb1.z,wb1.w), acc[11]);
    acc[12]=fmaf(nm, dotbf(hhi,wb2.x,wb2.y), acc[12]);
    acc[13]=fmaf(nm, dotbf(hhi,wb2.z,wb2.w), acc[13]);
    acc[14]=fmaf(nm, dotbf(hhi,wb3.x,wb3.y), acc[14]);
    acc[15]=fmaf(nm, dotbf(hhi,wb3.z,wb3.w), acc[15]);
    p = pn;
  }
  #pragma unroll
  for (int o=0;o<16;++o){ acc[o] += __shfl_xor(acc[o],16); acc[o] += __shfl_xor(acc[o],32); }
  if (g == 0){
    // block 2l -> cols 16l..16l+7 ; block 2l+1 -> cols 16l+8..16l+15
    #pragma unroll
    for (int q=0;q<4;++q){
      F4 o;
      #pragma unroll
      for (int j=0;j<4;++j) o.f[j]=acc[q*4+j];
      *(float4*)&agg[(size_t)wid*256 + l*16 + q*4] = o.v;
    }
  }
}

// ---------------- MFMA self-loop GEMMs (bf16 in, fp32 accum) ----------------
// A-frag (16x16x32): lane holds A[row=lane&15][k=(lane>>4)*8+j] -> 16B load from
// row-major bf16 A. B-frag pre-packed (Wp). C: col=lane&15, row=(lane>>4)*4+r.
__global__ __launch_bounds__(256)
void k_mfma_relu(const unsigned short* __restrict__ Ab, const unsigned short* __restrict__ Wp,
                 const float* __restrict__ agg, const float* __restrict__ bias,
                 unsigned short* __restrict__ outb, int M){
  const int lane = threadIdx.x & 63;
  const int rowBase = blockIdx.x*64 + (threadIdx.x>>6)*16;
  const int ar = lane & 15, kg = lane >> 4;
  const int aclamp = min(rowBase + ar, M-1);
  f4_t acc[8];
  #pragma unroll
  for (int ct=0; ct<8; ++ct) acc[ct] = (f4_t)0.f;
  #pragma unroll
  for (int ks=0; ks<4; ++ks){
    bf8_t a = *(const bf8_t*)&Ab[(size_t)aclamp*HD + ks*32 + kg*8];
    #pragma unroll
    for (int ct=0; ct<8; ++ct){
      bf8_t b = *(const bf8_t*)&Wp[(size_t)((ct*4 + ks)*64 + lane)*8];
      acc[ct] = __builtin_amdgcn_mfma_f32_16x16x32_bf16(a, b, acc[ct], 0,0,0);
    }
  }
  const int crow = rowBase + kg*4;
  #pragma unroll
  for (int r=0; r<4; ++r){
    int gr = crow + r;
    if (gr >= M) continue;
    #pragma unroll
    for (int ct=0; ct<8; ++ct){
      int col = ct*16 + ar;
      float v = fmaxf(acc[ct][r] + agg[(size_t)gr*128 + col] + bias[col], 0.f);
      outb[(size_t)gr*128 + col] = f2bf(v);
    }
  }
}

__global__ __launch_bounds__(256)
void k_mfma_gauss(const unsigned short* __restrict__ Ab, const unsigned short* __restrict__ Wp,
                  const float* __restrict__ agg, const float* __restrict__ bias,
                  const float* __restrict__ eps, float* __restrict__ out, int M){
  const int lane = threadIdx.x & 63;
  const int bx = blockIdx.x & 1;
  const int rowBase = (blockIdx.x>>1)*64 + (threadIdx.x>>6)*16;
  const int ar = lane & 15, kg = lane >> 4;
  const int aclamp = min(rowBase + ar, M-1);
  f4_t accm[4], acch[4];
  #pragma unroll
  for (int ct=0; ct<4; ++ct){ accm[ct] = (f4_t)0.f; acch[ct] = (f4_t)0.f; }
  #pragma unroll
  for (int ks=0; ks<4; ++ks){
    bf8_t a = *(const bf8_t*)&Ab[(size_t)aclamp*HD + ks*32 + kg*8];
    #pragma unroll
    for (int ct=0; ct<4; ++ct){
      int ctm = bx*4 + ct, cth = 8 + bx*4 + ct;
      bf8_t bm = *(const bf8_t*)&Wp[(size_t)((ctm*4 + ks)*64 + lane)*8];
      bf8_t bh = *(const bf8_t*)&Wp[(size_t)((cth*4 + ks)*64 + lane)*8];
      accm[ct] = __builtin_amdgcn_mfma_f32_16x16x32_bf16(a, bm, accm[ct], 0,0,0);
      acch[ct] = __builtin_amdgcn_mfma_f32_16x16x32_bf16(a, bh, acch[ct], 0,0,0);
    }
  }
  const int crow = rowBase + kg*4;
  #pragma unroll
  for (int r=0; r<4; ++r){
    int gr = crow + r;
    if (gr >= M) continue;
    #pragma unroll
    for (int ct=0; ct<4; ++ct){
      int colm = bx*64 + ct*16 + ar;
      float m  = accm[ct][r] + agg[(size_t)gr*256 + colm]       + bias[colm];
      float hp = acch[ct][r] + agg[(size_t)gr*256 + colm + 128] + bias[colm+128];
      float sp = fmaxf(hp, 0.f) + log1pf(expf(-fabsf(hp)));  // stable softplus
      out[(size_t)gr*128 + colm] = fmaf(sqrtf(sp + 1e-8f), eps[(size_t)gr*128 + colm], m);
    }
  }
}

extern "C" void kernel_launch(void* const* d_in, const int* in_sizes, int n_in,
                              void* d_out, int out_size, void* d_ws, size_t ws_size,
                              hipStream_t stream){
  (void)n_in; (void)out_size; (void)ws_size;
  const int*   node_ids = (const int*)d_in[0];
  const int*   src  = (const int*)d_in[1];
  const int*   dst  = (const int*)d_in[2];
  const int*   et   = (const int*)d_in[3];
  const float* norm = (const float*)d_in[4];
  const float* emb  = (const float*)d_in[5];
  const float* W1   = (const float*)d_in[6];
  const float* lw1  = (const float*)d_in[7];
  const float* b1   = (const float*)d_in[8];
  const float* W2   = (const float*)d_in[9];
  const float* lw2  = (const float*)d_in[10];
  const float* b2   = (const float*)d_in[11];
  const float* eps  = (const float*)d_in[12];
  float* out = (float*)d_out;

  const int N  = in_sizes[0];
  const int E  = in_sizes[1];
  const int n1 = in_sizes[6];    // R*B*4*4
  const int n2 = in_sizes[9];    // R*B*4*8

  // workspace layout (bytes):
  // [0, 2*szNH)        : agg2
  // [2*szNH, 3*szNH)   : (free)
  // [3*szNH, 4*szNH)   : agg1
  // then: pay | CSR ints | W1Tb | W2Tb (bf16) | W1p | W2p | h0b | h1b
  char* w = (char*)d_ws;
  size_t szNH = (size_t)N*HD*sizeof(float);
  float* agg2 = (float*)(w);
  float* agg1 = (float*)(w + 3*szNH);
  char*  ip   = w + 4*szNH;
  int4*  pay       = (int4*)ip;
  int*   counts    = (int*)(pay + E);
  int*   scanTmp   = counts + N;
  int*   row_ptr   = scanTmp + N;
  int*   cursors   = row_ptr + (N+1);
  int*   blockSums = cursors + N;
  size_t tail      = ((size_t)((char*)(blockSums + 1024) - w) + 63) & ~(size_t)63;
  unsigned short* W1Tb = (unsigned short*)(w + tail);
  unsigned short* W2Tb = W1Tb + n1;
  unsigned short* W1p  = W2Tb + n2;            //  8*256*8 ushorts
  unsigned short* W2p  = W1p + 8*256*8;        // 16*256*8 ushorts
  unsigned short* h0b  = W2p + 16*256*8;
  unsigned short* h1b  = h0b + (size_t)N*HD;

  hipMemsetAsync(counts, 0, (size_t)N*sizeof(int), stream);

  const int NG = N*32;
  const int Tprep = NG + E + n1 + n2 + 2048 + 4096;
  int nb_e    = (E+255)/256;
  int nb_scan = (N+255)/256;   // 391 (<1024, single-level top scan ok)

  k_prep<<<(Tprep+255)/256, 256, 0, stream>>>(node_ids, (const float4*)emb, h0b,
                                              dst, counts, W1, W1Tb, W2, W2Tb,
                                              lw1, W1p, lw2, W2p, NG, E, n1, n2);
  k_scan_block<<<nb_scan, 256, 0, stream>>>(counts, scanTmp, blockSums, N);
  k_scan_top<<<1, 1024, 0, stream>>>(blockSums, nb_scan);
  k_scan_fin<<<nb_scan, 256, 0, stream>>>(scanTmp, blockSums, counts, row_ptr, cursors, N);
  k_scatter<<<nb_e, 256, 0, stream>>>(dst, src, et, norm, cursors, pay, E);

  int nb_rows = (N+3)/4;        // one 64-lane wave per dst row, 4 waves/block
  int nb_m    = (N+63)/64;      // 64 rows per MFMA block

  k_edge1<<<nb_rows, 256, 0, stream>>>(row_ptr, pay, h0b, W1Tb, agg1, N);
  k_mfma_relu<<<nb_m, 256, 0, stream>>>(h0b, W1p, agg1, b1, h1b, N);
  k_edge2<<<nb_rows, 256, 0, stream>>>(row_ptr, pay, h1b, W2Tb, agg2, N);
  k_mfma_gauss<<<nb_m*2, 256, 0, stream>>>(h1b, W2p, agg2, b2, eps, out, N);
}